// Round 9
// baseline (686.647 us; speedup 1.0000x reference)
//
#include <hip/hip_runtime.h>

#define B 8
#define F 16
#define K 24
#define L 147456            // 384*384
#define CHUNK1 1024         // pixels per chunk
#define NCH1 144            // chunks per batch
#define TOTCH 1152          // B*NCH1
#define EPSF 1e-8f
#define DELTA_VAR 0.5f
#define DELTA_DIST 1.5f
#define GAMMA 0.001f

typedef float fx4 __attribute__((ext_vector_type(4)));
typedef short bf16x8 __attribute__((ext_vector_type(8)));
typedef float f32x4 __attribute__((ext_vector_type(4)));

// ---- Workspace (bytes) ----
//   sum_part float[TOTCH][F*K]   @ 0        : 1,769,472
//   cnt_part float[K][TOTCH]     @ 1769472  : 110,592
//   var_part float[K][TOTCH]     @ 1880064  : 110,592
//   counts   float[B*K]          @ 1990656  : 768
//   means    float[B*F*K]        @ 1991424  : 12,288
//   tickets  uint[2]             @ 2003712  : 256 (memset to 0 each launch)
//   labels   uint8[B*L]          @ 2003968  : 1,179,648
#define OFF_CNTP 1769472
#define OFF_VARP 1880064
#define OFF_CNT  1990656
#define OFF_MEAN 1991424
#define OFF_TKT  2003712
#define OFF_LAB  2003968

__device__ __forceinline__ short to_bf16(float v) {
    unsigned u = __float_as_uint(v);
    return (short)((u + 0x7FFFu + ((u >> 16) & 1u)) >> 16);   // RNE
}

// ---- K1: labels + counts + MFMA segment sums; last block -> counts, means ----
__global__ __launch_bounds__(256) void k1_sums(
        const float* __restrict__ t, const float* __restrict__ x,
        const int* __restrict__ ncl,
        unsigned char* __restrict__ labels, float* __restrict__ cnt_part,
        float* __restrict__ sum_part, float* __restrict__ counts,
        float* __restrict__ means, unsigned int* __restrict__ ticket) {
    const int gblk = blockIdx.x;          // b*NCH1 + ch
    const int b = gblk / NCH1;
    const int ch = gblk % NCH1;
    const int tid = threadIdx.x;
    const int wave = tid >> 6;
    const int lane = tid & 63;

    __shared__ unsigned char slab[CHUNK1];
    __shared__ float hist[4][32];
    __shared__ float sacc[4][F * K];

    if (lane < 32) hist[wave][lane] = 0.f;

    // ---- label phase: 4 px/thread, 24 independent NT float4 loads ----
    const int px = ch * CHUNK1 + tid * 4;
    const fx4* t4 = (const fx4*)t;
    int lab0 = 0, lab1 = 0, lab2 = 0, lab3 = 0;
    #pragma unroll
    for (int c = 0; c < K; ++c) {
        fx4 tv = __builtin_nontemporal_load(&t4[((size_t)(b * K + c) * L + px) >> 2]);
        lab0 += c * (tv.x > 0.5f);
        lab1 += c * (tv.y > 0.5f);
        lab2 += c * (tv.z > 0.5f);
        lab3 += c * (tv.w > 0.5f);
    }
    uchar4 lv = make_uchar4((unsigned char)lab0, (unsigned char)lab1,
                            (unsigned char)lab2, (unsigned char)lab3);
    *(uchar4*)&labels[(size_t)b * L + px] = lv;
    *(uchar4*)&slab[tid * 4] = lv;               // wave-private region
    atomicAdd(&hist[wave][lab0], 1.f);
    atomicAdd(&hist[wave][lab1], 1.f);
    atomicAdd(&hist[wave][lab2], 1.f);
    atomicAdd(&hist[wave][lab3], 1.f);
    __syncthreads();
    if (tid < K) {
        float v = hist[0][tid] + hist[1][tid] + hist[2][tid] + hist[3][tid];
        cnt_part[tid * TOTCH + gblk] = v;
    }

    // ---- MFMA phase: wave handles 256 px = 8 k-steps of 32 ----
    // Layouts verified (absmax 0.0 R5-R7): A[m=lane&15][k=q*8+j],
    // B[k][n=lane&15], D reg r = C[m=q*4+r][n].
    const int n = lane & 15;
    const int q = lane >> 4;
    f32x4 acc0 = {0.f, 0.f, 0.f, 0.f};
    f32x4 acc1 = {0.f, 0.f, 0.f, 0.f};
    const float* xr = x + (size_t)(b * F + n) * L + ch * CHUNK1 + wave * 256 + q * 8;
    const unsigned char* sl = slab + wave * 256 + q * 8;

    #pragma unroll 2
    for (int it = 0; it < 8; ++it) {
        fx4 xa = *(const fx4*)(xr + it * 32);
        fx4 xc = *(const fx4*)(xr + it * 32 + 4);
        unsigned l0 = *(const unsigned*)(sl + it * 32);
        unsigned l1 = *(const unsigned*)(sl + it * 32 + 4);

        bf16x8 afrag;
        afrag[0] = to_bf16(xa.x); afrag[1] = to_bf16(xa.y);
        afrag[2] = to_bf16(xa.z); afrag[3] = to_bf16(xa.w);
        afrag[4] = to_bf16(xc.x); afrag[5] = to_bf16(xc.y);
        afrag[6] = to_bf16(xc.z); afrag[7] = to_bf16(xc.w);

        bf16x8 bf0, bf1;
        #pragma unroll
        for (int j = 0; j < 8; ++j) {
            int lj = (j < 4) ? ((l0 >> (8 * j)) & 0xFF) : ((l1 >> (8 * (j - 4))) & 0xFF);
            bf0[j] = (lj == n)      ? (short)0x3F80 : (short)0;
            bf1[j] = (lj == n + 16) ? (short)0x3F80 : (short)0;
        }
        acc0 = __builtin_amdgcn_mfma_f32_16x16x32_bf16(afrag, bf0, acc0, 0, 0, 0);
        acc1 = __builtin_amdgcn_mfma_f32_16x16x32_bf16(afrag, bf1, acc1, 0, 0, 0);
    }

    #pragma unroll
    for (int r = 0; r < 4; ++r) {
        int f = q * 4 + r;
        sacc[wave][f * K + n] = acc0[r];
        if (n < 8) sacc[wave][f * K + 16 + n] = acc1[r];
    }
    __syncthreads();
    for (int i = tid; i < F * K; i += 256) {
        float v = sacc[0][i] + sacc[1][i] + sacc[2][i] + sacc[3][i];
        sum_part[(size_t)gblk * (F * K) + i] = v;
    }

    // ---- last-block tail: counts + means ----
    __threadfence();                      // release our partial stores
    __shared__ bool is_last;
    if (tid == 0) is_last = (atomicAdd(&ticket[0], 1u) == TOTCH - 1);
    __syncthreads();
    if (!is_last) return;
    __threadfence();                      // acquire all partials

    float* cs = sacc[0];                  // counts cache [192]
    if (tid < 192) {
        int bb = tid / K, c = tid % K;
        const float* row = cnt_part + c * TOTCH + bb * NCH1;
        float s = 0.f;
        #pragma unroll 4
        for (int j = 0; j < NCH1; ++j) s += row[j];
        cs[tid] = s;
        counts[tid] = s;
    }
    __syncthreads();
    for (int idx = tid; idx < B * F * K; idx += 256) {
        int bb = idx / (F * K);
        int r = idx % (F * K);
        float s = 0.f;
        const float* base = sum_part + (size_t)bb * NCH1 * (F * K) + r;
        #pragma unroll 4
        for (int j = 0; j < NCH1; ++j) s += base[(size_t)j * (F * K)];
        int c = r % K;
        float valid = (c < ncl[bb]) ? 1.f : 0.f;
        means[idx] = s / (cs[bb * K + c] + EPSF) * valid;
    }
}

// ---- K2: variance hinge; last block -> varsums + final loss ----
__global__ __launch_bounds__(256) void k2_var(
        const float* __restrict__ x, const unsigned char* __restrict__ labels,
        const float* __restrict__ means, const float* __restrict__ counts,
        const int* __restrict__ ncl, float* __restrict__ var_part,
        unsigned int* __restrict__ ticket, float* __restrict__ out) {
    const int gblk = blockIdx.x;          // b*NCH1 + ch
    const int b = gblk / NCH1;
    const int ch = gblk % NCH1;
    const int tid = threadIdx.x;
    const int wave = tid >> 6;
    const int lane = tid & 63;

    __shared__ float big[3072];           // main: means tile [384]; tail: all means
    __shared__ float hist[4][32];
    __shared__ float vs[192], cn[192], red[256];

    for (int i = tid; i < F * K; i += 256) big[i] = means[b * F * K + i];
    if (lane < 32) hist[wave][lane] = 0.f;
    __syncthreads();

    const int px = ch * CHUNK1 + tid * 4;
    uchar4 lv = *(const uchar4*)&labels[(size_t)b * L + px];
    float d0 = 0.f, d1 = 0.f, d2 = 0.f, d3 = 0.f;
    const fx4* x4 = (const fx4*)x;
    #pragma unroll
    for (int f = 0; f < F; ++f) {
        fx4 xv = x4[((size_t)(b * F + f) * L + px) >> 2];
        float u0 = xv.x - big[f * K + lv.x]; d0 += u0 * u0;
        float u1 = xv.y - big[f * K + lv.y]; d1 += u1 * u1;
        float u2 = xv.z - big[f * K + lv.z]; d2 += u2 * u2;
        float u3 = xv.w - big[f * K + lv.w]; d3 += u3 * u3;
    }
    float s0 = fmaxf(sqrtf(d0) - DELTA_VAR, 0.f); s0 *= s0;
    float s1 = fmaxf(sqrtf(d1) - DELTA_VAR, 0.f); s1 *= s1;
    float s2 = fmaxf(sqrtf(d2) - DELTA_VAR, 0.f); s2 *= s2;
    float s3 = fmaxf(sqrtf(d3) - DELTA_VAR, 0.f); s3 *= s3;
    atomicAdd(&hist[wave][lv.x], s0);
    atomicAdd(&hist[wave][lv.y], s1);
    atomicAdd(&hist[wave][lv.z], s2);
    atomicAdd(&hist[wave][lv.w], s3);
    __syncthreads();
    if (tid < K) {
        float v = hist[0][tid] + hist[1][tid] + hist[2][tid] + hist[3][tid];
        var_part[tid * TOTCH + gblk] = v;
    }

    // ---- last-block tail: varsums + loss ----
    __threadfence();
    __shared__ bool is_last;
    if (tid == 0) is_last = (atomicAdd(&ticket[1], 1u) == TOTCH - 1);
    __syncthreads();
    if (!is_last) return;
    __threadfence();

    for (int i = tid; i < B * F * K; i += 256) big[i] = means[i];
    if (tid < 192) {
        int bb = tid / K, c = tid % K;
        const float* row = var_part + c * TOTCH + bb * NCH1;
        float s = 0.f;
        #pragma unroll 4
        for (int j = 0; j < NCH1; ++j) s += row[j];
        vs[tid] = s;
        cn[tid] = counts[tid];
    }
    __syncthreads();

    float total = 0.f;
    for (int idx = tid; idx < B * K * K; idx += 256) {
        int bb = idx / (K * K);
        int r = idx % (K * K);
        int c = r / K;
        int d = r % K;
        int ncb = ncl[bb];
        float fnc = (float)ncb;
        if (d == 0 && c < ncb && ncb > 0) {
            float cv = vs[bb * K + c] / (cn[bb * K + c] + EPSF);
            total += cv / (fnc + EPSF) * (1.0f / B);
            float m2 = 0.f;
            #pragma unroll
            for (int f = 0; f < F; ++f) {
                float mv = big[(bb * F + f) * K + c];
                m2 += mv * mv;
            }
            total += GAMMA * sqrtf(m2) / fnc * (1.0f / B);
        }
        if (c != d && c < ncb && d < ncb && ncb > 1) {
            float pd2 = 0.f;
            #pragma unroll
            for (int f = 0; f < F; ++f) {
                float diff = big[(bb * F + f) * K + c] - big[(bb * F + f) * K + d];
                pd2 += diff * diff;
            }
            float h = fmaxf(2.f * DELTA_DIST - sqrtf(pd2), 0.f);
            total += h * h / (2.f * fnc * (fnc - 1.f) + EPSF) * (1.0f / B);
        }
    }
    red[tid] = total;
    __syncthreads();
    for (int s = 128; s > 0; s >>= 1) {
        if (tid < s) red[tid] += red[tid + s];
        __syncthreads();
    }
    if (tid == 0) out[0] = red[0];
}

extern "C" void kernel_launch(void* const* d_in, const int* in_sizes, int n_in,
                              void* d_out, int out_size, void* d_ws, size_t ws_size,
                              hipStream_t stream) {
    const float* x = (const float*)d_in[0];
    const float* t = (const float*)d_in[1];
    const int* ncl = (const int*)d_in[2];
    float* out = (float*)d_out;

    char* ws = (char*)d_ws;
    float* sum_part = (float*)ws;
    float* cnt_part = (float*)(ws + OFF_CNTP);
    float* var_part = (float*)(ws + OFF_VARP);
    float* counts   = (float*)(ws + OFF_CNT);
    float* means    = (float*)(ws + OFF_MEAN);
    unsigned int* tickets = (unsigned int*)(ws + OFF_TKT);
    unsigned char* labels = (unsigned char*)(ws + OFF_LAB);

    (void)hipMemsetAsync(tickets, 0, 256, stream);   // tickets must start at 0

    k1_sums<<<TOTCH, 256, 0, stream>>>(t, x, ncl, labels, cnt_part, sum_part,
                                       counts, means, tickets);
    k2_var <<<TOTCH, 256, 0, stream>>>(x, labels, means, counts, ncl,
                                       var_part, tickets, out);
}

// Round 10
// 261.900 us; speedup vs baseline: 2.6218x; 2.6218x over previous
//
#include <hip/hip_runtime.h>

#define B 8
#define F 16
#define K 24
#define L 147456            // 384*384
#define CHUNK1 1024         // pixels per chunk
#define NCH1 144            // chunks per batch
#define TOTCH 1152          // B*NCH1
#define EPSF 1e-8f
#define DELTA_VAR 0.5f
#define DELTA_DIST 1.5f
#define GAMMA 0.001f

typedef float fx4 __attribute__((ext_vector_type(4)));
typedef short bf16x8 __attribute__((ext_vector_type(8)));
typedef float f32x4 __attribute__((ext_vector_type(4)));

// ---- Workspace (bytes), no global atomics / fences anywhere ----
//   sum_part float[TOTCH][F*K]   @ 0        : 1,769,472
//   cnt_part float[K][TOTCH]     @ 1769472  : 110,592
//   var_part float[K][TOTCH]     @ 1880064  : 110,592
//   counts   float[B*K]          @ 1990656  : 768
//   means    float[B*F*K]        @ 1991424  : 12,288
//   labels   uint8[B*L]          @ 2003968  : 1,179,648
#define OFF_CNTP 1769472
#define OFF_VARP 1880064
#define OFF_CNT  1990656
#define OFF_MEAN 1991424
#define OFF_LAB  2003968

__device__ __forceinline__ short to_bf16(float v) {
    unsigned u = __float_as_uint(v);
    return (short)((u + 0x7FFFu + ((u >> 16) & 1u)) >> 16);   // RNE
}

// ---- K1: labels + counts + MFMA segment sums. launch_bounds(256,2) gives the
// register allocator a 256-VGPR budget so the 24 t-loads and 16 x-loads stay
// in flight as register arrays (the VGPR-32 serialization was the R3/R5/R7
// latency binding). ----
__global__ __launch_bounds__(256, 2) void k1_sums(
        const float* __restrict__ t, const float* __restrict__ x,
        unsigned char* __restrict__ labels, float* __restrict__ cnt_part,
        float* __restrict__ sum_part) {
    const int gblk = blockIdx.x;          // b*NCH1 + ch
    const int b = gblk / NCH1;
    const int ch = gblk % NCH1;
    const int tid = threadIdx.x;
    const int wave = tid >> 6;
    const int lane = tid & 63;

    __shared__ unsigned char slab[CHUNK1];
    __shared__ float hist[4][32];
    __shared__ float sacc[4][F * K];

    if (lane < 32) hist[wave][lane] = 0.f;

    // ---- label phase: ALL 24 NT float4 loads issued back-to-back ----
    const int px = ch * CHUNK1 + tid * 4;
    const fx4* t4 = (const fx4*)t;
    fx4 tv[K];
    #pragma unroll
    for (int c = 0; c < K; ++c)
        tv[c] = __builtin_nontemporal_load(&t4[((size_t)(b * K + c) * L + px) >> 2]);

    int lab0 = 0, lab1 = 0, lab2 = 0, lab3 = 0;
    #pragma unroll
    for (int c = 0; c < K; ++c) {
        lab0 += c * (tv[c].x > 0.5f);
        lab1 += c * (tv[c].y > 0.5f);
        lab2 += c * (tv[c].z > 0.5f);
        lab3 += c * (tv[c].w > 0.5f);
    }
    uchar4 lv = make_uchar4((unsigned char)lab0, (unsigned char)lab1,
                            (unsigned char)lab2, (unsigned char)lab3);
    *(uchar4*)&labels[(size_t)b * L + px] = lv;
    *(uchar4*)&slab[tid * 4] = lv;
    atomicAdd(&hist[wave][lab0], 1.f);
    atomicAdd(&hist[wave][lab1], 1.f);
    atomicAdd(&hist[wave][lab2], 1.f);
    atomicAdd(&hist[wave][lab3], 1.f);
    __syncthreads();
    if (tid < K) {
        float v = hist[0][tid] + hist[1][tid] + hist[2][tid] + hist[3][tid];
        cnt_part[tid * TOTCH + gblk] = v;
    }

    // ---- MFMA phase: ALL 16 x float4 loads issued up front ----
    // Layouts verified (absmax 0.0 R5-R9): A[m=lane&15][k=q*8+j],
    // B[k][n=lane&15], D reg r = C[m=q*4+r][n].
    const int n = lane & 15;
    const int q = lane >> 4;
    const float* xr = x + (size_t)(b * F + n) * L + ch * CHUNK1 + wave * 256 + q * 8;
    fx4 xv[16];
    #pragma unroll
    for (int it = 0; it < 8; ++it) {
        xv[2 * it]     = *(const fx4*)(xr + it * 32);
        xv[2 * it + 1] = *(const fx4*)(xr + it * 32 + 4);
    }

    const unsigned char* sl = slab + wave * 256 + q * 8;
    f32x4 acc0 = {0.f, 0.f, 0.f, 0.f};
    f32x4 acc1 = {0.f, 0.f, 0.f, 0.f};
    #pragma unroll
    for (int it = 0; it < 8; ++it) {
        unsigned l0 = *(const unsigned*)(sl + it * 32);
        unsigned l1 = *(const unsigned*)(sl + it * 32 + 4);
        fx4 xa = xv[2 * it], xc = xv[2 * it + 1];

        bf16x8 afrag;
        afrag[0] = to_bf16(xa.x); afrag[1] = to_bf16(xa.y);
        afrag[2] = to_bf16(xa.z); afrag[3] = to_bf16(xa.w);
        afrag[4] = to_bf16(xc.x); afrag[5] = to_bf16(xc.y);
        afrag[6] = to_bf16(xc.z); afrag[7] = to_bf16(xc.w);

        bf16x8 bf0, bf1;
        #pragma unroll
        for (int j = 0; j < 8; ++j) {
            int lj = (j < 4) ? ((l0 >> (8 * j)) & 0xFF) : ((l1 >> (8 * (j - 4))) & 0xFF);
            bf0[j] = (lj == n)      ? (short)0x3F80 : (short)0;
            bf1[j] = (lj == n + 16) ? (short)0x3F80 : (short)0;
        }
        acc0 = __builtin_amdgcn_mfma_f32_16x16x32_bf16(afrag, bf0, acc0, 0, 0, 0);
        acc1 = __builtin_amdgcn_mfma_f32_16x16x32_bf16(afrag, bf1, acc1, 0, 0, 0);
    }

    #pragma unroll
    for (int r = 0; r < 4; ++r) {
        int f = q * 4 + r;
        sacc[wave][f * K + n] = acc0[r];
        if (n < 8) sacc[wave][f * K + 16 + n] = acc1[r];
    }
    __syncthreads();
    for (int i = tid; i < F * K; i += 256) {
        float v = sacc[0][i] + sacc[1][i] + sacc[2][i] + sacc[3][i];
        sum_part[(size_t)gblk * (F * K) + i] = v;
    }
}

// ---- K2: counts + means, one block per batch ----
__global__ __launch_bounds__(256) void k2_means(const float* __restrict__ cnt_part,
                                                const float* __restrict__ sum_part,
                                                const int* __restrict__ ncl,
                                                float* __restrict__ counts,
                                                float* __restrict__ means) {
    const int b = blockIdx.x;
    const int tid = threadIdx.x;
    __shared__ float cl[8][K];
    __shared__ float cs[K];

    if (tid < 192) {
        int c = tid >> 3, grp = tid & 7;
        const float* row = cnt_part + c * TOTCH + b * NCH1 + grp * 18;
        float s = 0.f;
        #pragma unroll
        for (int j = 0; j < 18; ++j) s += row[j];
        cl[grp][c] = s;
    }
    __syncthreads();
    if (tid < K) {
        float s = 0.f;
        #pragma unroll
        for (int g = 0; g < 8; ++g) s += cl[g][tid];
        cs[tid] = s;
        counts[b * K + tid] = s;
    }
    __syncthreads();
    const int ncb = ncl[b];
    for (int r = tid; r < F * K; r += 256) {
        float s = 0.f;
        const float* base = sum_part + (size_t)b * NCH1 * (F * K) + r;
        #pragma unroll 4
        for (int j = 0; j < NCH1; ++j) s += base[(size_t)j * (F * K)];
        int c = r % K;
        float valid = (c < ncb) ? 1.f : 0.f;
        means[b * F * K + r] = s / (cs[c] + EPSF) * valid;
    }
}

// ---- K3: variance hinge, 4 px/thread, all 16 x-loads batched ----
__global__ __launch_bounds__(256, 2) void k3_var(
        const float* __restrict__ x, const unsigned char* __restrict__ labels,
        const float* __restrict__ means, float* __restrict__ var_part) {
    const int gblk = blockIdx.x;          // b*NCH1 + ch
    const int b = gblk / NCH1;
    const int ch = gblk % NCH1;
    const int tid = threadIdx.x;
    const int wave = tid >> 6;
    const int lane = tid & 63;

    __shared__ float m[F * K];
    __shared__ float hist[4][32];

    const int px = ch * CHUNK1 + tid * 4;
    uchar4 lv = *(const uchar4*)&labels[(size_t)b * L + px];
    const fx4* x4 = (const fx4*)x;
    fx4 xv[F];
    #pragma unroll
    for (int f = 0; f < F; ++f)
        xv[f] = x4[((size_t)(b * F + f) * L + px) >> 2];

    for (int i = tid; i < F * K; i += 256) m[i] = means[b * F * K + i];
    if (lane < 32) hist[wave][lane] = 0.f;
    __syncthreads();

    float d0 = 0.f, d1 = 0.f, d2 = 0.f, d3 = 0.f;
    #pragma unroll
    for (int f = 0; f < F; ++f) {
        float u0 = xv[f].x - m[f * K + lv.x]; d0 += u0 * u0;
        float u1 = xv[f].y - m[f * K + lv.y]; d1 += u1 * u1;
        float u2 = xv[f].z - m[f * K + lv.z]; d2 += u2 * u2;
        float u3 = xv[f].w - m[f * K + lv.w]; d3 += u3 * u3;
    }
    float s0 = fmaxf(sqrtf(d0) - DELTA_VAR, 0.f); s0 *= s0;
    float s1 = fmaxf(sqrtf(d1) - DELTA_VAR, 0.f); s1 *= s1;
    float s2 = fmaxf(sqrtf(d2) - DELTA_VAR, 0.f); s2 *= s2;
    float s3 = fmaxf(sqrtf(d3) - DELTA_VAR, 0.f); s3 *= s3;
    atomicAdd(&hist[wave][lv.x], s0);
    atomicAdd(&hist[wave][lv.y], s1);
    atomicAdd(&hist[wave][lv.z], s2);
    atomicAdd(&hist[wave][lv.w], s3);
    __syncthreads();
    if (tid < K) {
        float v = hist[0][tid] + hist[1][tid] + hist[2][tid] + hist[3][tid];
        var_part[tid * TOTCH + gblk] = v;
    }
}

// ---- K4: varsum reduce + final loss, one block ----
__global__ __launch_bounds__(256) void k4_finish(
        const float* __restrict__ var_part, const float* __restrict__ means,
        const float* __restrict__ counts, const int* __restrict__ ncl,
        float* __restrict__ out) {
    __shared__ float big[B * F * K];
    __shared__ float vs[192], cn[192], red[256];
    const int tid = threadIdx.x;

    for (int i = tid; i < B * F * K; i += 256) big[i] = means[i];
    if (tid < 192) {
        int bb = tid / K, c = tid % K;
        const float* row = var_part + c * TOTCH + bb * NCH1;
        float s = 0.f;
        #pragma unroll 4
        for (int j = 0; j < NCH1; ++j) s += row[j];
        vs[tid] = s;
        cn[tid] = counts[tid];
    }
    __syncthreads();

    float total = 0.f;
    for (int idx = tid; idx < B * K * K; idx += 256) {
        int bb = idx / (K * K);
        int r = idx % (K * K);
        int c = r / K;
        int d = r % K;
        int ncb = ncl[bb];
        float fnc = (float)ncb;
        if (d == 0 && c < ncb && ncb > 0) {
            float cv = vs[bb * K + c] / (cn[bb * K + c] + EPSF);
            total += cv / (fnc + EPSF) * (1.0f / B);
            float m2 = 0.f;
            #pragma unroll
            for (int f = 0; f < F; ++f) {
                float mv = big[(bb * F + f) * K + c];
                m2 += mv * mv;
            }
            total += GAMMA * sqrtf(m2) / fnc * (1.0f / B);
        }
        if (c != d && c < ncb && d < ncb && ncb > 1) {
            float pd2 = 0.f;
            #pragma unroll
            for (int f = 0; f < F; ++f) {
                float diff = big[(bb * F + f) * K + c] - big[(bb * F + f) * K + d];
                pd2 += diff * diff;
            }
            float h = fmaxf(2.f * DELTA_DIST - sqrtf(pd2), 0.f);
            total += h * h / (2.f * fnc * (fnc - 1.f) + EPSF) * (1.0f / B);
        }
    }
    red[tid] = total;
    __syncthreads();
    for (int s = 128; s > 0; s >>= 1) {
        if (tid < s) red[tid] += red[tid + s];
        __syncthreads();
    }
    if (tid == 0) out[0] = red[0];
}

extern "C" void kernel_launch(void* const* d_in, const int* in_sizes, int n_in,
                              void* d_out, int out_size, void* d_ws, size_t ws_size,
                              hipStream_t stream) {
    const float* x = (const float*)d_in[0];
    const float* t = (const float*)d_in[1];
    const int* ncl = (const int*)d_in[2];
    float* out = (float*)d_out;

    char* ws = (char*)d_ws;
    float* sum_part = (float*)ws;
    float* cnt_part = (float*)(ws + OFF_CNTP);
    float* var_part = (float*)(ws + OFF_VARP);
    float* counts   = (float*)(ws + OFF_CNT);
    float* means    = (float*)(ws + OFF_MEAN);
    unsigned char* labels = (unsigned char*)(ws + OFF_LAB);

    k1_sums <<<TOTCH, 256, 0, stream>>>(t, x, labels, cnt_part, sum_part);
    k2_means<<<B, 256, 0, stream>>>(cnt_part, sum_part, ncl, counts, means);
    k3_var  <<<TOTCH, 256, 0, stream>>>(x, labels, means, var_part);
    k4_finish<<<1, 256, 0, stream>>>(var_part, means, counts, ncl, out);
}

// Round 11
// 243.585 us; speedup vs baseline: 2.8189x; 1.0752x over previous
//
#include <hip/hip_runtime.h>

#define B 8
#define F 16
#define K 24
#define L 147456            // 384*384
#define CHUNK1 1024         // pixels per chunk
#define NCH1 144            // chunks per batch
#define TOTCH 1152          // B*NCH1
#define EPSF 1e-8f
#define DELTA_VAR 0.5f
#define DELTA_DIST 1.5f
#define GAMMA 0.001f

typedef float fx4 __attribute__((ext_vector_type(4)));
typedef short bf16x8 __attribute__((ext_vector_type(8)));
typedef float f32x4 __attribute__((ext_vector_type(4)));

// ---- Workspace (bytes), no global atomics / fences ----
//   sum_part float[F*K][TOTCH]   @ 0        : 1,769,472   (TRANSPOSED: row r contiguous)
//   cnt_part float[K][TOTCH]     @ 1769472  : 110,592
//   var_part float[K][TOTCH]     @ 1880064  : 110,592
//   counts   float[B*K]          @ 1990656  : 768
//   means    float[B*F*K]        @ 1991424  : 12,288
//   labels   uint8[B*L]          @ 2003968  : 1,179,648
#define OFF_CNTP 1769472
#define OFF_VARP 1880064
#define OFF_CNT  1990656
#define OFF_MEAN 1991424
#define OFF_LAB  2003968

__device__ __forceinline__ short to_bf16(float v) {
    unsigned u = __float_as_uint(v);
    return (short)((u + 0x7FFFu + ((u >> 16) & 1u)) >> 16);   // RNE
}

// ---- K1: labels + counts + MFMA segment sums ----
// sched_barrier(0) after each load batch FORCES the loads to issue before any
// use (a launch_bounds cap alone is not a floor — R9 showed the allocator
// shrinking to 40 VGPR and serializing). x-loads are issued first: they drain
// behind the whole label phase.
__global__ __launch_bounds__(256, 3) void k1_sums(
        const float* __restrict__ t, const float* __restrict__ x,
        unsigned char* __restrict__ labels, float* __restrict__ cnt_part,
        float* __restrict__ sum_part) {
    const int gblk = blockIdx.x;          // b*NCH1 + ch
    const int b = gblk / NCH1;
    const int ch = gblk % NCH1;
    const int tid = threadIdx.x;
    const int wave = tid >> 6;
    const int lane = tid & 63;
    const int n = lane & 15;
    const int q = lane >> 4;

    __shared__ unsigned char slab[CHUNK1];
    __shared__ float hist[4][32];
    __shared__ float sacc[4][F * K];

    if (lane < 32) hist[wave][lane] = 0.f;

    // ---- issue ALL 16 x float4 loads first (consumed after the sync) ----
    const float* xr = x + (size_t)(b * F + n) * L + ch * CHUNK1 + wave * 256 + q * 8;
    fx4 xv[16];
    #pragma unroll
    for (int it = 0; it < 8; ++it) {
        xv[2 * it]     = *(const fx4*)(xr + it * 32);
        xv[2 * it + 1] = *(const fx4*)(xr + it * 32 + 4);
    }
    __builtin_amdgcn_sched_barrier(0);

    // ---- label phase: 3 batches of 8 NT float4 loads, forced in flight ----
    const int px = ch * CHUNK1 + tid * 4;
    const fx4* t4 = (const fx4*)t;
    int lab0 = 0, lab1 = 0, lab2 = 0, lab3 = 0;
    #pragma unroll
    for (int h = 0; h < 3; ++h) {
        fx4 tv[8];
        #pragma unroll
        for (int j = 0; j < 8; ++j)
            tv[j] = __builtin_nontemporal_load(
                &t4[((size_t)(b * K + h * 8 + j) * L + px) >> 2]);
        __builtin_amdgcn_sched_barrier(0);
        #pragma unroll
        for (int j = 0; j < 8; ++j) {
            int c = h * 8 + j;
            lab0 += c * (tv[j].x > 0.5f);
            lab1 += c * (tv[j].y > 0.5f);
            lab2 += c * (tv[j].z > 0.5f);
            lab3 += c * (tv[j].w > 0.5f);
        }
    }
    uchar4 lv = make_uchar4((unsigned char)lab0, (unsigned char)lab1,
                            (unsigned char)lab2, (unsigned char)lab3);
    *(uchar4*)&labels[(size_t)b * L + px] = lv;
    *(uchar4*)&slab[tid * 4] = lv;
    atomicAdd(&hist[wave][lab0], 1.f);
    atomicAdd(&hist[wave][lab1], 1.f);
    atomicAdd(&hist[wave][lab2], 1.f);
    atomicAdd(&hist[wave][lab3], 1.f);
    __syncthreads();
    if (tid < K) {
        float v = hist[0][tid] + hist[1][tid] + hist[2][tid] + hist[3][tid];
        cnt_part[tid * TOTCH + gblk] = v;
    }

    // ---- MFMA phase (x already in registers) ----
    // Layouts verified (absmax 0.0 R5-R10): A[m=lane&15][k=q*8+j],
    // B[k][n=lane&15], D reg r = C[m=q*4+r][n].
    const unsigned char* sl = slab + wave * 256 + q * 8;
    f32x4 acc0 = {0.f, 0.f, 0.f, 0.f};
    f32x4 acc1 = {0.f, 0.f, 0.f, 0.f};
    #pragma unroll
    for (int it = 0; it < 8; ++it) {
        unsigned l0 = *(const unsigned*)(sl + it * 32);
        unsigned l1 = *(const unsigned*)(sl + it * 32 + 4);
        fx4 xa = xv[2 * it], xc = xv[2 * it + 1];

        bf16x8 afrag;
        afrag[0] = to_bf16(xa.x); afrag[1] = to_bf16(xa.y);
        afrag[2] = to_bf16(xa.z); afrag[3] = to_bf16(xa.w);
        afrag[4] = to_bf16(xc.x); afrag[5] = to_bf16(xc.y);
        afrag[6] = to_bf16(xc.z); afrag[7] = to_bf16(xc.w);

        bf16x8 bf0, bf1;
        #pragma unroll
        for (int j = 0; j < 8; ++j) {
            int lj = (j < 4) ? ((l0 >> (8 * j)) & 0xFF) : ((l1 >> (8 * (j - 4))) & 0xFF);
            bf0[j] = (lj == n)      ? (short)0x3F80 : (short)0;
            bf1[j] = (lj == n + 16) ? (short)0x3F80 : (short)0;
        }
        acc0 = __builtin_amdgcn_mfma_f32_16x16x32_bf16(afrag, bf0, acc0, 0, 0, 0);
        acc1 = __builtin_amdgcn_mfma_f32_16x16x32_bf16(afrag, bf1, acc1, 0, 0, 0);
    }

    #pragma unroll
    for (int r = 0; r < 4; ++r) {
        int f = q * 4 + r;
        sacc[wave][f * K + n] = acc0[r];
        if (n < 8) sacc[wave][f * K + 16 + n] = acc1[r];
    }
    __syncthreads();
    for (int i = tid; i < F * K; i += 256) {
        float v = sacc[0][i] + sacc[1][i] + sacc[2][i] + sacc[3][i];
        sum_part[(size_t)i * TOTCH + gblk] = v;   // transposed (scatter, hidden)
    }
}

// ---- K2: one wave per (b, f*K+c) row. 3072 waves, fully parallel. ----
__global__ __launch_bounds__(256) void k2_means(const float* __restrict__ cnt_part,
                                                const float* __restrict__ sum_part,
                                                const int* __restrict__ ncl,
                                                float* __restrict__ counts,
                                                float* __restrict__ means) {
    const int idx = blockIdx.x * 4 + (threadIdx.x >> 6);   // row id, 0..3071
    const int lane = threadIdx.x & 63;
    const int b = idx / (F * K);
    const int r = idx % (F * K);
    const int c = r % K;

    const float* crow = cnt_part + c * TOTCH + b * NCH1;
    const float* srow = sum_part + (size_t)r * TOTCH + b * NCH1;
    float cv = crow[lane] + crow[lane + 64] + ((lane < 16) ? crow[lane + 128] : 0.f);
    float sv = srow[lane] + srow[lane + 64] + ((lane < 16) ? srow[lane + 128] : 0.f);
    #pragma unroll
    for (int off = 32; off > 0; off >>= 1) {
        cv += __shfl_down(cv, off);
        sv += __shfl_down(sv, off);
    }
    if (lane == 0) {
        if (r < K) counts[b * K + c] = cv;       // f==0 waves own the counts
        float valid = (c < ncl[b]) ? 1.f : 0.f;
        means[b * F * K + r] = sv / (cv + EPSF) * valid;
    }
}

// ---- K3: variance hinge, 4 px/thread, forced-in-flight x loads ----
__global__ __launch_bounds__(256, 4) void k3_var(
        const float* __restrict__ x, const unsigned char* __restrict__ labels,
        const float* __restrict__ means, float* __restrict__ var_part) {
    const int gblk = blockIdx.x;          // b*NCH1 + ch
    const int b = gblk / NCH1;
    const int ch = gblk % NCH1;
    const int tid = threadIdx.x;
    const int wave = tid >> 6;
    const int lane = tid & 63;

    __shared__ float m[F * K];
    __shared__ float hist[4][32];

    const int px = ch * CHUNK1 + tid * 4;
    uchar4 lv = *(const uchar4*)&labels[(size_t)b * L + px];
    const fx4* x4 = (const fx4*)x;
    fx4 xv[F];
    #pragma unroll
    for (int f = 0; f < F; ++f)
        xv[f] = x4[((size_t)(b * F + f) * L + px) >> 2];
    __builtin_amdgcn_sched_barrier(0);

    for (int i = tid; i < F * K; i += 256) m[i] = means[b * F * K + i];
    if (lane < 32) hist[wave][lane] = 0.f;
    __syncthreads();

    float d0 = 0.f, d1 = 0.f, d2 = 0.f, d3 = 0.f;
    #pragma unroll
    for (int f = 0; f < F; ++f) {
        float u0 = xv[f].x - m[f * K + lv.x]; d0 += u0 * u0;
        float u1 = xv[f].y - m[f * K + lv.y]; d1 += u1 * u1;
        float u2 = xv[f].z - m[f * K + lv.z]; d2 += u2 * u2;
        float u3 = xv[f].w - m[f * K + lv.w]; d3 += u3 * u3;
    }
    float s0 = fmaxf(sqrtf(d0) - DELTA_VAR, 0.f); s0 *= s0;
    float s1 = fmaxf(sqrtf(d1) - DELTA_VAR, 0.f); s1 *= s1;
    float s2 = fmaxf(sqrtf(d2) - DELTA_VAR, 0.f); s2 *= s2;
    float s3 = fmaxf(sqrtf(d3) - DELTA_VAR, 0.f); s3 *= s3;
    atomicAdd(&hist[wave][lv.x], s0);
    atomicAdd(&hist[wave][lv.y], s1);
    atomicAdd(&hist[wave][lv.z], s2);
    atomicAdd(&hist[wave][lv.w], s3);
    __syncthreads();
    if (tid < K) {
        float v = hist[0][tid] + hist[1][tid] + hist[2][tid] + hist[3][tid];
        var_part[tid * TOTCH + gblk] = v;
    }
}

// ---- K4: varsum reduce + final loss, one block ----
__global__ __launch_bounds__(256) void k4_finish(
        const float* __restrict__ var_part, const float* __restrict__ means,
        const float* __restrict__ counts, const int* __restrict__ ncl,
        float* __restrict__ out) {
    __shared__ float big[B * F * K];
    __shared__ float vs[192], cn[192], red[256];
    const int tid = threadIdx.x;

    for (int i = tid; i < B * F * K; i += 256) big[i] = means[i];
    if (tid < 192) {
        int bb = tid / K, c = tid % K;
        const float* row = var_part + c * TOTCH + bb * NCH1;
        float s = 0.f;
        #pragma unroll 8
        for (int j = 0; j < NCH1; ++j) s += row[j];
        vs[tid] = s;
        cn[tid] = counts[tid];
    }
    __syncthreads();

    float total = 0.f;
    for (int idx = tid; idx < B * K * K; idx += 256) {
        int bb = idx / (K * K);
        int r = idx % (K * K);
        int c = r / K;
        int d = r % K;
        int ncb = ncl[bb];
        float fnc = (float)ncb;
        if (d == 0 && c < ncb && ncb > 0) {
            float cv = vs[bb * K + c] / (cn[bb * K + c] + EPSF);
            total += cv / (fnc + EPSF) * (1.0f / B);
            float m2 = 0.f;
            #pragma unroll
            for (int f = 0; f < F; ++f) {
                float mv = big[(bb * F + f) * K + c];
                m2 += mv * mv;
            }
            total += GAMMA * sqrtf(m2) / fnc * (1.0f / B);
        }
        if (c != d && c < ncb && d < ncb && ncb > 1) {
            float pd2 = 0.f;
            #pragma unroll
            for (int f = 0; f < F; ++f) {
                float diff = big[(bb * F + f) * K + c] - big[(bb * F + f) * K + d];
                pd2 += diff * diff;
            }
            float h = fmaxf(2.f * DELTA_DIST - sqrtf(pd2), 0.f);
            total += h * h / (2.f * fnc * (fnc - 1.f) + EPSF) * (1.0f / B);
        }
    }
    red[tid] = total;
    __syncthreads();
    for (int s = 128; s > 0; s >>= 1) {
        if (tid < s) red[tid] += red[tid + s];
        __syncthreads();
    }
    if (tid == 0) out[0] = red[0];
}

extern "C" void kernel_launch(void* const* d_in, const int* in_sizes, int n_in,
                              void* d_out, int out_size, void* d_ws, size_t ws_size,
                              hipStream_t stream) {
    const float* x = (const float*)d_in[0];
    const float* t = (const float*)d_in[1];
    const int* ncl = (const int*)d_in[2];
    float* out = (float*)d_out;

    char* ws = (char*)d_ws;
    float* sum_part = (float*)ws;
    float* cnt_part = (float*)(ws + OFF_CNTP);
    float* var_part = (float*)(ws + OFF_VARP);
    float* counts   = (float*)(ws + OFF_CNT);
    float* means    = (float*)(ws + OFF_MEAN);
    unsigned char* labels = (unsigned char*)(ws + OFF_LAB);

    k1_sums <<<TOTCH, 256, 0, stream>>>(t, x, labels, cnt_part, sum_part);
    k2_means<<<768, 256, 0, stream>>>(cnt_part, sum_part, ncl, counts, means);
    k3_var  <<<TOTCH, 256, 0, stream>>>(x, labels, means, var_part);
    k4_finish<<<1, 256, 0, stream>>>(var_part, means, counts, ncl, out);
}

// Round 12
// 241.307 us; speedup vs baseline: 2.8455x; 1.0094x over previous
//
#include <hip/hip_runtime.h>

#define B 8
#define F 16
#define K 24
#define L 147456            // 384*384
#define CHUNK1 1024         // pixels per chunk
#define NCH1 144            // chunks per batch
#define TOTCH 1152          // B*NCH1
#define EPSF 1e-8f
#define DELTA_VAR 0.5f
#define DELTA_DIST 1.5f
#define GAMMA 0.001f

typedef float fx4 __attribute__((ext_vector_type(4)));
typedef short bf16x8 __attribute__((ext_vector_type(8)));
typedef float f32x4 __attribute__((ext_vector_type(4)));

// ---- Workspace (bytes), no global atomics / fences ----
//   sum_part float[TOTCH][F*K]   @ 0        : 1,769,472  (row-major, coalesced stores)
//   cnt_part float[K][TOTCH]     @ 1769472  : 110,592
//   var_part float[K][TOTCH]     @ 1880064  : 110,592
//   counts   float[B*K]          @ 1990656  : 768
//   varsums  float[B*K]          @ 1991424  : 768
//   means    float[B*F*K]        @ 1992192  : 12,288
//   labels   uint8[B*L]          @ 2004480  : 1,179,648
#define OFF_CNTP 1769472
#define OFF_VARP 1880064
#define OFF_CNT  1990656
#define OFF_VSUM 1991424
#define OFF_MEAN 1992192
#define OFF_LAB  2004480

__device__ __forceinline__ short to_bf16(float v) {
    unsigned u = __float_as_uint(v);
    return (short)((u + 0x7FFFu + ((u >> 16) & 1u)) >> 16);   // RNE
}

// ---- K1: labels + counts + MFMA segment sums. XCD-swizzled: b = blk&7 so
// each XCD (round-robin dispatch heuristic) works one batch -> L2 locality
// for k3's re-read. sched_barrier(0) forces load batches to stay in flight.
__global__ __launch_bounds__(256, 3) void k1_sums(
        const float* __restrict__ t, const float* __restrict__ x,
        unsigned char* __restrict__ labels, float* __restrict__ cnt_part,
        float* __restrict__ sum_part) {
    const int b = blockIdx.x & 7;         // XCD swizzle
    const int ch = blockIdx.x >> 3;
    const int gblk = b * NCH1 + ch;       // logical chunk id (storage index)
    const int tid = threadIdx.x;
    const int wave = tid >> 6;
    const int lane = tid & 63;
    const int n = lane & 15;
    const int q = lane >> 4;

    __shared__ unsigned char slab[CHUNK1];
    __shared__ float hist[4][32];
    __shared__ float sacc[4][F * K];

    if (lane < 32) hist[wave][lane] = 0.f;

    // ---- issue ALL 16 x float4 loads first (consumed in MFMA phase) ----
    const float* xr = x + (size_t)(b * F + n) * L + ch * CHUNK1 + wave * 256 + q * 8;
    fx4 xv[16];
    #pragma unroll
    for (int it = 0; it < 8; ++it) {
        xv[2 * it]     = *(const fx4*)(xr + it * 32);
        xv[2 * it + 1] = *(const fx4*)(xr + it * 32 + 4);
    }
    __builtin_amdgcn_sched_barrier(0);

    // ---- label phase: 3 batches of 8 NT float4 loads, forced in flight ----
    const int px = ch * CHUNK1 + tid * 4;
    const fx4* t4 = (const fx4*)t;
    int lab0 = 0, lab1 = 0, lab2 = 0, lab3 = 0;
    #pragma unroll
    for (int h = 0; h < 3; ++h) {
        fx4 tv[8];
        #pragma unroll
        for (int j = 0; j < 8; ++j)
            tv[j] = __builtin_nontemporal_load(
                &t4[((size_t)(b * K + h * 8 + j) * L + px) >> 2]);
        __builtin_amdgcn_sched_barrier(0);
        #pragma unroll
        for (int j = 0; j < 8; ++j) {
            int c = h * 8 + j;
            lab0 += c * (tv[j].x > 0.5f);
            lab1 += c * (tv[j].y > 0.5f);
            lab2 += c * (tv[j].z > 0.5f);
            lab3 += c * (tv[j].w > 0.5f);
        }
    }
    uchar4 lv = make_uchar4((unsigned char)lab0, (unsigned char)lab1,
                            (unsigned char)lab2, (unsigned char)lab3);
    *(uchar4*)&labels[(size_t)b * L + px] = lv;
    *(uchar4*)&slab[tid * 4] = lv;
    atomicAdd(&hist[wave][lab0], 1.f);
    atomicAdd(&hist[wave][lab1], 1.f);
    atomicAdd(&hist[wave][lab2], 1.f);
    atomicAdd(&hist[wave][lab3], 1.f);
    __syncthreads();
    if (tid < K) {
        float v = hist[0][tid] + hist[1][tid] + hist[2][tid] + hist[3][tid];
        cnt_part[tid * TOTCH + gblk] = v;
    }

    // ---- MFMA phase (x already in registers) ----
    // Layouts verified (absmax 0.0 R5-R11): A[m=lane&15][k=q*8+j],
    // B[k][n=lane&15], D reg r = C[m=q*4+r][n].
    const unsigned char* sl = slab + wave * 256 + q * 8;
    f32x4 acc0 = {0.f, 0.f, 0.f, 0.f};
    f32x4 acc1 = {0.f, 0.f, 0.f, 0.f};
    #pragma unroll
    for (int it = 0; it < 8; ++it) {
        unsigned l0 = *(const unsigned*)(sl + it * 32);
        unsigned l1 = *(const unsigned*)(sl + it * 32 + 4);
        fx4 xa = xv[2 * it], xc = xv[2 * it + 1];

        bf16x8 afrag;
        afrag[0] = to_bf16(xa.x); afrag[1] = to_bf16(xa.y);
        afrag[2] = to_bf16(xa.z); afrag[3] = to_bf16(xa.w);
        afrag[4] = to_bf16(xc.x); afrag[5] = to_bf16(xc.y);
        afrag[6] = to_bf16(xc.z); afrag[7] = to_bf16(xc.w);

        bf16x8 bf0, bf1;
        #pragma unroll
        for (int j = 0; j < 8; ++j) {
            int lj = (j < 4) ? ((l0 >> (8 * j)) & 0xFF) : ((l1 >> (8 * (j - 4))) & 0xFF);
            bf0[j] = (lj == n)      ? (short)0x3F80 : (short)0;
            bf1[j] = (lj == n + 16) ? (short)0x3F80 : (short)0;
        }
        acc0 = __builtin_amdgcn_mfma_f32_16x16x32_bf16(afrag, bf0, acc0, 0, 0, 0);
        acc1 = __builtin_amdgcn_mfma_f32_16x16x32_bf16(afrag, bf1, acc1, 0, 0, 0);
    }

    #pragma unroll
    for (int r = 0; r < 4; ++r) {
        int f = q * 4 + r;
        sacc[wave][f * K + n] = acc0[r];
        if (n < 8) sacc[wave][f * K + 16 + n] = acc1[r];
    }
    __syncthreads();
    for (int i = tid; i < F * K; i += 256) {
        float v = sacc[0][i] + sacc[1][i] + sacc[2][i] + sacc[3][i];
        sum_part[(size_t)gblk * (F * K) + i] = v;   // coalesced row-major store
    }
}

// ---- K2: one wave per (b, f*K+c) row. 3072 waves. Strided reads, L2-hot. ----
__global__ __launch_bounds__(256) void k2_means(const float* __restrict__ cnt_part,
                                                const float* __restrict__ sum_part,
                                                const int* __restrict__ ncl,
                                                float* __restrict__ counts,
                                                float* __restrict__ means) {
    const int idx = blockIdx.x * 4 + (threadIdx.x >> 6);   // row id, 0..3071
    const int lane = threadIdx.x & 63;
    const int b = idx / (F * K);
    const int r = idx % (F * K);
    const int c = r % K;

    const float* crow = cnt_part + c * TOTCH + b * NCH1;       // contiguous
    const float* srow = sum_part + (size_t)(b * NCH1) * (F * K) + r;  // stride F*K
    float cv = crow[lane] + crow[lane + 64] + ((lane < 16) ? crow[lane + 128] : 0.f);
    float sv = srow[(size_t)lane * (F * K)] + srow[(size_t)(lane + 64) * (F * K)]
             + ((lane < 16) ? srow[(size_t)(lane + 128) * (F * K)] : 0.f);
    #pragma unroll
    for (int off = 32; off > 0; off >>= 1) {
        cv += __shfl_down(cv, off);
        sv += __shfl_down(sv, off);
    }
    if (lane == 0) {
        if (r < K) counts[b * K + c] = cv;       // f==0 waves own the counts
        float valid = (c < ncl[b]) ? 1.f : 0.f;
        means[b * F * K + r] = sv / (cv + EPSF) * valid;
    }
}

// ---- K3: variance hinge, 4 px/thread, XCD-swizzled like k1 ----
__global__ __launch_bounds__(256, 4) void k3_var(
        const float* __restrict__ x, const unsigned char* __restrict__ labels,
        const float* __restrict__ means, float* __restrict__ var_part) {
    const int b = blockIdx.x & 7;         // same XCD swizzle as k1
    const int ch = blockIdx.x >> 3;
    const int gblk = b * NCH1 + ch;
    const int tid = threadIdx.x;
    const int wave = tid >> 6;
    const int lane = tid & 63;

    __shared__ float m[F * K];
    __shared__ float hist[4][32];

    const int px = ch * CHUNK1 + tid * 4;
    uchar4 lv = *(const uchar4*)&labels[(size_t)b * L + px];
    const fx4* x4 = (const fx4*)x;
    fx4 xv[F];
    #pragma unroll
    for (int f = 0; f < F; ++f)
        xv[f] = x4[((size_t)(b * F + f) * L + px) >> 2];
    __builtin_amdgcn_sched_barrier(0);

    for (int i = tid; i < F * K; i += 256) m[i] = means[b * F * K + i];
    if (lane < 32) hist[wave][lane] = 0.f;
    __syncthreads();

    float d0 = 0.f, d1 = 0.f, d2 = 0.f, d3 = 0.f;
    #pragma unroll
    for (int f = 0; f < F; ++f) {
        float u0 = xv[f].x - m[f * K + lv.x]; d0 += u0 * u0;
        float u1 = xv[f].y - m[f * K + lv.y]; d1 += u1 * u1;
        float u2 = xv[f].z - m[f * K + lv.z]; d2 += u2 * u2;
        float u3 = xv[f].w - m[f * K + lv.w]; d3 += u3 * u3;
    }
    float s0 = fmaxf(sqrtf(d0) - DELTA_VAR, 0.f); s0 *= s0;
    float s1 = fmaxf(sqrtf(d1) - DELTA_VAR, 0.f); s1 *= s1;
    float s2 = fmaxf(sqrtf(d2) - DELTA_VAR, 0.f); s2 *= s2;
    float s3 = fmaxf(sqrtf(d3) - DELTA_VAR, 0.f); s3 *= s3;
    atomicAdd(&hist[wave][lv.x], s0);
    atomicAdd(&hist[wave][lv.y], s1);
    atomicAdd(&hist[wave][lv.z], s2);
    atomicAdd(&hist[wave][lv.w], s3);
    __syncthreads();
    if (tid < K) {
        float v = hist[0][tid] + hist[1][tid] + hist[2][tid] + hist[3][tid];
        var_part[tid * TOTCH + gblk] = v;
    }
}

// ---- K3r: parallel varsum reduce — one wave per (b,c), coalesced rows ----
__global__ __launch_bounds__(256) void k3r_reduce(const float* __restrict__ var_part,
                                                  float* __restrict__ varsums) {
    const int bc = blockIdx.x * 4 + (threadIdx.x >> 6);   // 0..191
    const int lane = threadIdx.x & 63;
    const int b = bc / K;
    const int c = bc % K;
    const float* row = var_part + c * TOTCH + b * NCH1;   // contiguous 144
    float s = row[lane] + row[lane + 64] + ((lane < 16) ? row[lane + 128] : 0.f);
    #pragma unroll
    for (int off = 32; off > 0; off >>= 1) s += __shfl_down(s, off);
    if (lane == 0) varsums[bc] = s;
}

// ---- K4: final loss, one block, tiny reads only ----
__global__ __launch_bounds__(256) void k4_finish(
        const float* __restrict__ varsums, const float* __restrict__ means,
        const float* __restrict__ counts, const int* __restrict__ ncl,
        float* __restrict__ out) {
    __shared__ float big[B * F * K];
    __shared__ float vs[192], cn[192], red[256];
    const int tid = threadIdx.x;

    for (int i = tid; i < B * F * K; i += 256) big[i] = means[i];
    if (tid < 192) {
        vs[tid] = varsums[tid];
        cn[tid] = counts[tid];
    }
    __syncthreads();

    float total = 0.f;
    for (int idx = tid; idx < B * K * K; idx += 256) {
        int bb = idx / (K * K);
        int r = idx % (K * K);
        int c = r / K;
        int d = r % K;
        int ncb = ncl[bb];
        float fnc = (float)ncb;
        if (d == 0 && c < ncb && ncb > 0) {
            float cv = vs[bb * K + c] / (cn[bb * K + c] + EPSF);
            total += cv / (fnc + EPSF) * (1.0f / B);
            float m2 = 0.f;
            #pragma unroll
            for (int f = 0; f < F; ++f) {
                float mv = big[(bb * F + f) * K + c];
                m2 += mv * mv;
            }
            total += GAMMA * sqrtf(m2) / fnc * (1.0f / B);
        }
        if (c != d && c < ncb && d < ncb && ncb > 1) {
            float pd2 = 0.f;
            #pragma unroll
            for (int f = 0; f < F; ++f) {
                float diff = big[(bb * F + f) * K + c] - big[(bb * F + f) * K + d];
                pd2 += diff * diff;
            }
            float h = fmaxf(2.f * DELTA_DIST - sqrtf(pd2), 0.f);
            total += h * h / (2.f * fnc * (fnc - 1.f) + EPSF) * (1.0f / B);
        }
    }
    red[tid] = total;
    __syncthreads();
    for (int s = 128; s > 0; s >>= 1) {
        if (tid < s) red[tid] += red[tid + s];
        __syncthreads();
    }
    if (tid == 0) out[0] = red[0];
}

extern "C" void kernel_launch(void* const* d_in, const int* in_sizes, int n_in,
                              void* d_out, int out_size, void* d_ws, size_t ws_size,
                              hipStream_t stream) {
    const float* x = (const float*)d_in[0];
    const float* t = (const float*)d_in[1];
    const int* ncl = (const int*)d_in[2];
    float* out = (float*)d_out;

    char* ws = (char*)d_ws;
    float* sum_part = (float*)ws;
    float* cnt_part = (float*)(ws + OFF_CNTP);
    float* var_part = (float*)(ws + OFF_VARP);
    float* counts   = (float*)(ws + OFF_CNT);
    float* varsums  = (float*)(ws + OFF_VSUM);
    float* means    = (float*)(ws + OFF_MEAN);
    unsigned char* labels = (unsigned char*)(ws + OFF_LAB);

    k1_sums   <<<TOTCH, 256, 0, stream>>>(t, x, labels, cnt_part, sum_part);
    k2_means  <<<768, 256, 0, stream>>>(cnt_part, sum_part, ncl, counts, means);
    k3_var    <<<TOTCH, 256, 0, stream>>>(x, labels, means, var_part);
    k3r_reduce<<<48, 256, 0, stream>>>(var_part, varsums);
    k4_finish <<<1, 256, 0, stream>>>(varsums, means, counts, ncl, out);
}

// Round 13
// 241.136 us; speedup vs baseline: 2.8476x; 1.0007x over previous
//
#include <hip/hip_runtime.h>

#define B 8
#define F 16
#define K 24
#define L 147456            // 384*384
#define CHUNK1 1024         // pixels per chunk
#define NCH1 144            // chunks per batch
#define TOTCH 1152          // B*NCH1
#define EPSF 1e-8f
#define DELTA_VAR 0.5f
#define DELTA_DIST 1.5f
#define GAMMA 0.001f

typedef float fx4 __attribute__((ext_vector_type(4)));
typedef short bf16x8 __attribute__((ext_vector_type(8)));
typedef float f32x4 __attribute__((ext_vector_type(4)));

// ---- Workspace (bytes), no global atomics / fences ----
//   sum_part float[TOTCH][F*K]   @ 0        : 1,769,472  (row-major, coalesced stores)
//   cnt_part float[K][TOTCH]     @ 1769472  : 110,592
//   var_part float[K][TOTCH]     @ 1880064  : 110,592
//   counts   float[B*K]          @ 1990656  : 768
//   varsums  float[B*K]          @ 1991424  : 768
//   means    float[B*F*K]        @ 1992192  : 12,288
//   labels   uint8[B*L]          @ 2004480  : 1,179,648
#define OFF_CNTP 1769472
#define OFF_VARP 1880064
#define OFF_CNT  1990656
#define OFF_VSUM 1991424
#define OFF_MEAN 1992192
#define OFF_LAB  2004480

__device__ __forceinline__ short to_bf16(float v) {
    unsigned u = __float_as_uint(v);
    return (short)((u + 0x7FFFu + ((u >> 16) & 1u)) >> 16);   // RNE
}

// ---- K1: labels + counts + MFMA segment sums ----
// Single 24-deep t-load batch (one vmcnt drain instead of three); x-loads
// issued before __syncthreads so they drain behind the barrier + LDS phase.
// tv[] dies at the compares, xv[] lives after -> peak VGPR fits (256,3).
__global__ __launch_bounds__(256, 3) void k1_sums(
        const float* __restrict__ t, const float* __restrict__ x,
        unsigned char* __restrict__ labels, float* __restrict__ cnt_part,
        float* __restrict__ sum_part) {
    const int b = blockIdx.x & 7;         // XCD swizzle (R12)
    const int ch = blockIdx.x >> 3;
    const int gblk = b * NCH1 + ch;       // storage index
    const int tid = threadIdx.x;
    const int wave = tid >> 6;
    const int lane = tid & 63;
    const int n = lane & 15;
    const int q = lane >> 4;

    __shared__ unsigned char slab[CHUNK1];
    __shared__ float hist[4][32];
    __shared__ float sacc[4][F * K];

    if (lane < 32) hist[wave][lane] = 0.f;

    // ---- label phase: ALL 24 NT float4 loads in one batch ----
    const int px = ch * CHUNK1 + tid * 4;
    const fx4* t4 = (const fx4*)t;
    fx4 tv[K];
    #pragma unroll
    for (int c = 0; c < K; ++c)
        tv[c] = __builtin_nontemporal_load(&t4[((size_t)(b * K + c) * L + px) >> 2]);
    __builtin_amdgcn_sched_barrier(0);

    int lab0 = 0, lab1 = 0, lab2 = 0, lab3 = 0;
    #pragma unroll
    for (int c = 0; c < K; ++c) {
        lab0 += c * (tv[c].x > 0.5f);
        lab1 += c * (tv[c].y > 0.5f);
        lab2 += c * (tv[c].z > 0.5f);
        lab3 += c * (tv[c].w > 0.5f);
    }
    uchar4 lv = make_uchar4((unsigned char)lab0, (unsigned char)lab1,
                            (unsigned char)lab2, (unsigned char)lab3);
    *(uchar4*)&labels[(size_t)b * L + px] = lv;
    *(uchar4*)&slab[tid * 4] = lv;
    atomicAdd(&hist[wave][lab0], 1.f);
    atomicAdd(&hist[wave][lab1], 1.f);
    atomicAdd(&hist[wave][lab2], 1.f);
    atomicAdd(&hist[wave][lab3], 1.f);

    // ---- issue 16 x float4 loads now: they drain behind the barrier ----
    __builtin_amdgcn_sched_barrier(0);
    const float* xr = x + (size_t)(b * F + n) * L + ch * CHUNK1 + wave * 256 + q * 8;
    fx4 xv[16];
    #pragma unroll
    for (int it = 0; it < 8; ++it) {
        xv[2 * it]     = *(const fx4*)(xr + it * 32);
        xv[2 * it + 1] = *(const fx4*)(xr + it * 32 + 4);
    }
    __builtin_amdgcn_sched_barrier(0);

    __syncthreads();
    if (tid < K) {
        float v = hist[0][tid] + hist[1][tid] + hist[2][tid] + hist[3][tid];
        cnt_part[tid * TOTCH + gblk] = v;
    }

    // ---- MFMA phase (x in registers, labels in LDS) ----
    // Layouts verified (absmax 0.0 R5-R12): A[m=lane&15][k=q*8+j],
    // B[k][n=lane&15], D reg r = C[m=q*4+r][n].
    const unsigned char* sl = slab + wave * 256 + q * 8;
    f32x4 acc0 = {0.f, 0.f, 0.f, 0.f};
    f32x4 acc1 = {0.f, 0.f, 0.f, 0.f};
    #pragma unroll
    for (int it = 0; it < 8; ++it) {
        unsigned l0 = *(const unsigned*)(sl + it * 32);
        unsigned l1 = *(const unsigned*)(sl + it * 32 + 4);
        fx4 xa = xv[2 * it], xc = xv[2 * it + 1];

        bf16x8 afrag;
        afrag[0] = to_bf16(xa.x); afrag[1] = to_bf16(xa.y);
        afrag[2] = to_bf16(xa.z); afrag[3] = to_bf16(xa.w);
        afrag[4] = to_bf16(xc.x); afrag[5] = to_bf16(xc.y);
        afrag[6] = to_bf16(xc.z); afrag[7] = to_bf16(xc.w);

        bf16x8 bf0, bf1;
        #pragma unroll
        for (int j = 0; j < 8; ++j) {
            int lj = (j < 4) ? ((l0 >> (8 * j)) & 0xFF) : ((l1 >> (8 * (j - 4))) & 0xFF);
            bf0[j] = (lj == n)      ? (short)0x3F80 : (short)0;
            bf1[j] = (lj == n + 16) ? (short)0x3F80 : (short)0;
        }
        acc0 = __builtin_amdgcn_mfma_f32_16x16x32_bf16(afrag, bf0, acc0, 0, 0, 0);
        acc1 = __builtin_amdgcn_mfma_f32_16x16x32_bf16(afrag, bf1, acc1, 0, 0, 0);
    }

    #pragma unroll
    for (int r = 0; r < 4; ++r) {
        int f = q * 4 + r;
        sacc[wave][f * K + n] = acc0[r];
        if (n < 8) sacc[wave][f * K + 16 + n] = acc1[r];
    }
    __syncthreads();
    for (int i = tid; i < F * K; i += 256) {
        float v = sacc[0][i] + sacc[1][i] + sacc[2][i] + sacc[3][i];
        sum_part[(size_t)gblk * (F * K) + i] = v;   // coalesced row-major store
    }
}

// ---- K2: one wave per (b, f*K+c) row. 3072 waves. ----
__global__ __launch_bounds__(256) void k2_means(const float* __restrict__ cnt_part,
                                                const float* __restrict__ sum_part,
                                                const int* __restrict__ ncl,
                                                float* __restrict__ counts,
                                                float* __restrict__ means) {
    const int idx = blockIdx.x * 4 + (threadIdx.x >> 6);   // row id, 0..3071
    const int lane = threadIdx.x & 63;
    const int b = idx / (F * K);
    const int r = idx % (F * K);
    const int c = r % K;

    const float* crow = cnt_part + c * TOTCH + b * NCH1;
    const float* srow = sum_part + (size_t)(b * NCH1) * (F * K) + r;
    float cv = crow[lane] + crow[lane + 64] + ((lane < 16) ? crow[lane + 128] : 0.f);
    float sv = srow[(size_t)lane * (F * K)] + srow[(size_t)(lane + 64) * (F * K)]
             + ((lane < 16) ? srow[(size_t)(lane + 128) * (F * K)] : 0.f);
    #pragma unroll
    for (int off = 32; off > 0; off >>= 1) {
        cv += __shfl_down(cv, off);
        sv += __shfl_down(sv, off);
    }
    if (lane == 0) {
        if (r < K) counts[b * K + c] = cv;
        float valid = (c < ncl[b]) ? 1.f : 0.f;
        means[b * F * K + r] = sv / (cv + EPSF) * valid;
    }
}

// ---- K3: variance hinge, 4 px/thread, XCD-swizzled like k1 ----
__global__ __launch_bounds__(256, 4) void k3_var(
        const float* __restrict__ x, const unsigned char* __restrict__ labels,
        const float* __restrict__ means, float* __restrict__ var_part) {
    const int b = blockIdx.x & 7;
    const int ch = blockIdx.x >> 3;
    const int gblk = b * NCH1 + ch;
    const int tid = threadIdx.x;
    const int wave = tid >> 6;
    const int lane = tid & 63;

    __shared__ float m[F * K];
    __shared__ float hist[4][32];

    const int px = ch * CHUNK1 + tid * 4;
    uchar4 lv = *(const uchar4*)&labels[(size_t)b * L + px];
    const fx4* x4 = (const fx4*)x;
    fx4 xv[F];
    #pragma unroll
    for (int f = 0; f < F; ++f)
        xv[f] = x4[((size_t)(b * F + f) * L + px) >> 2];
    __builtin_amdgcn_sched_barrier(0);

    for (int i = tid; i < F * K; i += 256) m[i] = means[b * F * K + i];
    if (lane < 32) hist[wave][lane] = 0.f;
    __syncthreads();

    float d0 = 0.f, d1 = 0.f, d2 = 0.f, d3 = 0.f;
    #pragma unroll
    for (int f = 0; f < F; ++f) {
        float u0 = xv[f].x - m[f * K + lv.x]; d0 += u0 * u0;
        float u1 = xv[f].y - m[f * K + lv.y]; d1 += u1 * u1;
        float u2 = xv[f].z - m[f * K + lv.z]; d2 += u2 * u2;
        float u3 = xv[f].w - m[f * K + lv.w]; d3 += u3 * u3;
    }
    float s0 = fmaxf(sqrtf(d0) - DELTA_VAR, 0.f); s0 *= s0;
    float s1 = fmaxf(sqrtf(d1) - DELTA_VAR, 0.f); s1 *= s1;
    float s2 = fmaxf(sqrtf(d2) - DELTA_VAR, 0.f); s2 *= s2;
    float s3 = fmaxf(sqrtf(d3) - DELTA_VAR, 0.f); s3 *= s3;
    atomicAdd(&hist[wave][lv.x], s0);
    atomicAdd(&hist[wave][lv.y], s1);
    atomicAdd(&hist[wave][lv.z], s2);
    atomicAdd(&hist[wave][lv.w], s3);
    __syncthreads();
    if (tid < K) {
        float v = hist[0][tid] + hist[1][tid] + hist[2][tid] + hist[3][tid];
        var_part[tid * TOTCH + gblk] = v;
    }
}

// ---- K3r: parallel varsum reduce — one wave per (b,c) ----
__global__ __launch_bounds__(256) void k3r_reduce(const float* __restrict__ var_part,
                                                  float* __restrict__ varsums) {
    const int bc = blockIdx.x * 4 + (threadIdx.x >> 6);   // 0..191
    const int lane = threadIdx.x & 63;
    const int b = bc / K;
    const int c = bc % K;
    const float* row = var_part + c * TOTCH + b * NCH1;
    float s = row[lane] + row[lane + 64] + ((lane < 16) ? row[lane + 128] : 0.f);
    #pragma unroll
    for (int off = 32; off > 0; off >>= 1) s += __shfl_down(s, off);
    if (lane == 0) varsums[bc] = s;
}

// ---- K4: final loss, one block, tiny reads only ----
__global__ __launch_bounds__(256) void k4_finish(
        const float* __restrict__ varsums, const float* __restrict__ means,
        const float* __restrict__ counts, const int* __restrict__ ncl,
        float* __restrict__ out) {
    __shared__ float big[B * F * K];
    __shared__ float vs[192], cn[192], red[256];
    const int tid = threadIdx.x;

    for (int i = tid; i < B * F * K; i += 256) big[i] = means[i];
    if (tid < 192) {
        vs[tid] = varsums[tid];
        cn[tid] = counts[tid];
    }
    __syncthreads();

    float total = 0.f;
    for (int idx = tid; idx < B * K * K; idx += 256) {
        int bb = idx / (K * K);
        int r = idx % (K * K);
        int c = r / K;
        int d = r % K;
        int ncb = ncl[bb];
        float fnc = (float)ncb;
        if (d == 0 && c < ncb && ncb > 0) {
            float cv = vs[bb * K + c] / (cn[bb * K + c] + EPSF);
            total += cv / (fnc + EPSF) * (1.0f / B);
            float m2 = 0.f;
            #pragma unroll
            for (int f = 0; f < F; ++f) {
                float mv = big[(bb * F + f) * K + c];
                m2 += mv * mv;
            }
            total += GAMMA * sqrtf(m2) / fnc * (1.0f / B);
        }
        if (c != d && c < ncb && d < ncb && ncb > 1) {
            float pd2 = 0.f;
            #pragma unroll
            for (int f = 0; f < F; ++f) {
                float diff = big[(bb * F + f) * K + c] - big[(bb * F + f) * K + d];
                pd2 += diff * diff;
            }
            float h = fmaxf(2.f * DELTA_DIST - sqrtf(pd2), 0.f);
            total += h * h / (2.f * fnc * (fnc - 1.f) + EPSF) * (1.0f / B);
        }
    }
    red[tid] = total;
    __syncthreads();
    for (int s = 128; s > 0; s >>= 1) {
        if (tid < s) red[tid] += red[tid + s];
        __syncthreads();
    }
    if (tid == 0) out[0] = red[0];
}

extern "C" void kernel_launch(void* const* d_in, const int* in_sizes, int n_in,
                              void* d_out, int out_size, void* d_ws, size_t ws_size,
                              hipStream_t stream) {
    const float* x = (const float*)d_in[0];
    const float* t = (const float*)d_in[1];
    const int* ncl = (const int*)d_in[2];
    float* out = (float*)d_out;

    char* ws = (char*)d_ws;
    float* sum_part = (float*)ws;
    float* cnt_part = (float*)(ws + OFF_CNTP);
    float* var_part = (float*)(ws + OFF_VARP);
    float* counts   = (float*)(ws + OFF_CNT);
    float* varsums  = (float*)(ws + OFF_VSUM);
    float* means    = (float*)(ws + OFF_MEAN);
    unsigned char* labels = (unsigned char*)(ws + OFF_LAB);

    k1_sums   <<<TOTCH, 256, 0, stream>>>(t, x, labels, cnt_part, sum_part);
    k2_means  <<<768, 256, 0, stream>>>(cnt_part, sum_part, ncl, counts, means);
    k3_var    <<<TOTCH, 256, 0, stream>>>(x, labels, means, var_part);
    k3r_reduce<<<48, 256, 0, stream>>>(var_part, varsums);
    k4_finish <<<1, 256, 0, stream>>>(varsums, means, counts, ncl, out);
}